// Round 7
// baseline (309.691 us; speedup 1.0000x reference)
//
#include <hip/hip_runtime.h>
#include <math.h>

// MultiheadAttention: B=2, T=S=2048, C=1024, H=16, D=64
// ws layout (ushort units), path A (ws >= 64MB):
//   qh[4M] kh[4M] vt[4M] ao[4M] xbf[12M] wbf[4M]  = 64 MB
// qh/kh: [B*H][L][D]; vt: [B*H][D][S]; qh pre-scaled by log2(e)/sqrt(D).
// xbf: bf16 copies of query/key/value; wbf: bf16 Wq,Wk,Wv,Wo.
// Path B (fallback, ws < 64MB): R6 kernels (fp32 LDS staging).

typedef __attribute__((ext_vector_type(4))) float f32x4;
typedef __attribute__((ext_vector_type(8))) __bf16 bf16x8;
typedef __attribute__((ext_vector_type(4))) unsigned int u32x4;
typedef __attribute__((ext_vector_type(2))) unsigned int u32x2;
typedef __attribute__((ext_vector_type(4))) unsigned short u16x4;

#define MFMA16(a, b, c) __builtin_amdgcn_mfma_f32_16x16x32_bf16(a, b, c, 0, 0, 0)

static __device__ __forceinline__ unsigned short f2bf(float f) {
    __bf16 h = (__bf16)f;
    return __builtin_bit_cast(unsigned short, h);
}
static __device__ __forceinline__ unsigned int pack2bf_fast(float a, float b) {
    unsigned int ua = __builtin_bit_cast(unsigned int, a) + 0x8000u;
    unsigned int ub = __builtin_bit_cast(unsigned int, b) + 0x8000u;
    return (ua >> 16) | (ub & 0xffff0000u);
}
static __device__ __forceinline__ bf16x8 cvt8(f32x4 a, f32x4 b) {
    bf16x8 t;
#pragma unroll
    for (int e = 0; e < 4; e++) { t[e] = (__bf16)a[e]; t[e + 4] = (__bf16)b[e]; }
    return t;
}

#define GLL(gptr, lptr) \
    __builtin_amdgcn_global_load_lds( \
        (const __attribute__((address_space(1))) unsigned int*)(gptr), \
        (__attribute__((address_space(3))) unsigned int*)(lptr), 16, 0, 0)

// ---------------------------------------------------------------------------
// Kernel 0 (path A): fp32 -> bf16 pre-convert of X (q,k,v) and W (q,k,v,o).
// Pure bandwidth pass (~96 MB), removes all fp32 handling from the GEMMs.
// ---------------------------------------------------------------------------
__global__ __launch_bounds__(256)
void cvt_kernel(const float* __restrict__ xq, const float* __restrict__ xk,
                const float* __restrict__ xv,
                const float* __restrict__ wq, const float* __restrict__ wk,
                const float* __restrict__ wv, const float* __restrict__ wo,
                unsigned short* __restrict__ xbf, unsigned short* __restrict__ wbf)
{
    const int t = blockIdx.y;  // 0..6
    const float* src;
    unsigned short* dst;
    int n;
    if (t < 3) {
        src = (t == 0) ? xq : (t == 1) ? xk : xv;
        dst = xbf + (size_t)t * 4194304;
        n = 4194304;
    } else {
        int u = t - 3;
        src = (u == 0) ? wq : (u == 1) ? wk : (u == 2) ? wv : wo;
        dst = wbf + (size_t)u * 1048576;
        n = 1048576;
    }
    for (int i = (blockIdx.x * 256 + threadIdx.x) * 4; i < n; i += gridDim.x * 1024) {
        f32x4 x = *(const f32x4*)(src + i);
        u16x4 h;
#pragma unroll
        for (int e = 0; e < 4; e++) h[e] = f2bf(x[e]);
        *(u16x4*)(dst + i) = h;
    }
}

// ---------------------------------------------------------------------------
// Kernel 1 (path A): QKV projections, pure bf16 m97-shape GEMM.
// DMA: inst j covers 16 rows (1 KB); lane i -> row j*16+(i>>2), slot i&3
// holds global chunk (i&3)^((i>>2)&3); frag slot = quad^(row&3).
// z=0 (Q, pre-scaled log2e/8), z=1 (K): out [B,H,L,D]. z=2 (V): out [B,H,D,S].
// launch_bounds(256,3): grid 768 = exactly 3 blocks/CU co-resident.
// ---------------------------------------------------------------------------
__global__ __launch_bounds__(256, 3)
void proj_qkv_bf16_kernel(const unsigned short* __restrict__ xbf,
                          const unsigned short* __restrict__ wbf,
                          const float* __restrict__ bq, const float* __restrict__ bk,
                          const float* __restrict__ bv,
                          unsigned short* __restrict__ qh, unsigned short* __restrict__ kh,
                          unsigned short* __restrict__ vt)
{
    const int z = blockIdx.z;
    const unsigned short* X = xbf + (size_t)z * 4194304;
    const unsigned short* W = wbf + (size_t)z * 1048576;
    const float* bias = (z == 0) ? bq : (z == 1) ? bk : bv;
    unsigned short* O = (z == 0) ? qh : (z == 1) ? kh : vt;
    const float scale = (z == 0) ? 0.18033688011112042f : 1.0f;

    __shared__ unsigned short As[128 * 32];  // 8 KB, chunk-swizzled
    __shared__ unsigned short Bs[128 * 32];

    const int tid  = threadIdx.x;
    const int lane = tid & 63;
    const int w    = tid >> 6;
    const int l16  = lane & 15;
    const int quad = lane >> 4;
    const int wm   = (w >> 1) * 64;
    const int wn   = (w & 1) * 64;
    const int m0   = blockIdx.y * 128;
    const int n0   = blockIdx.x * 128;

    const int rhi = lane >> 2;                 // row in 16-row group
    const int cg  = (lane & 3) ^ (rhi & 3);    // global chunk for this lane

    f32x4 acc[4][4];
#pragma unroll
    for (int i = 0; i < 4; i++)
#pragma unroll
        for (int j = 0; j < 4; j++) {
            f32x4 zv = {0.0f, 0.0f, 0.0f, 0.0f};
            acc[i][j] = zv;
        }

    const int sl = (quad ^ (l16 & 3)) * 8;  // frag slot offset (ushorts)

    for (int k0 = 0; k0 < 1024; k0 += 32) {
#pragma unroll
        for (int r = 0; r < 2; r++) {
            int j = w * 2 + r;  // 0..7, 16 rows each
            GLL(X + (size_t)(m0 + j * 16 + rhi) * 1024 + k0 + cg * 8, &As[j * 512]);
            GLL(W + (size_t)(n0 + j * 16 + rhi) * 1024 + k0 + cg * 8, &Bs[j * 512]);
        }
        __syncthreads();

        bf16x8 af[4], bfr[4];
#pragma unroll
        for (int mi = 0; mi < 4; mi++)
            af[mi] = *(const bf16x8*)(&As[(wm + mi * 16 + l16) * 32 + sl]);
#pragma unroll
        for (int ni = 0; ni < 4; ni++)
            bfr[ni] = *(const bf16x8*)(&Bs[(wn + ni * 16 + l16) * 32 + sl]);
        if (z != 2) {
#pragma unroll
            for (int mi = 0; mi < 4; mi++)
#pragma unroll
                for (int ni = 0; ni < 4; ni++)
                    acc[mi][ni] = MFMA16(af[mi], bfr[ni], acc[mi][ni]);
        } else {
#pragma unroll
            for (int mi = 0; mi < 4; mi++)
#pragma unroll
                for (int ni = 0; ni < 4; ni++)
                    acc[mi][ni] = MFMA16(bfr[ni], af[mi], acc[mi][ni]);
        }
        __syncthreads();
    }

    if (z != 2) {
#pragma unroll
        for (int ni = 0; ni < 4; ni++) {
            int gn = n0 + wn + ni * 16 + l16;
            float bval = bias[gn];
            int h = gn >> 6, d = gn & 63;
#pragma unroll
            for (int mi = 0; mi < 4; mi++) {
#pragma unroll
                for (int r = 0; r < 4; r++) {
                    int gm = m0 + wm + mi * 16 + quad * 4 + r;
                    int b = gm >> 11, l = gm & 2047;
                    float val = (acc[mi][ni][r] + bval) * scale;
                    O[(((size_t)(b * 16 + h) * 2048 + l) * 64) + d] = f2bf(val);
                }
            }
        }
    } else {
#pragma unroll
        for (int ni = 0; ni < 4; ni++) {
#pragma unroll
            for (int r = 0; r < 4; r++) {
                int gn = n0 + wn + ni * 16 + quad * 4 + r;
                float bval = bias[gn];
                int h = gn >> 6, d = gn & 63;
#pragma unroll
                for (int mi = 0; mi < 4; mi++) {
                    int gm = m0 + wm + mi * 16 + l16;
                    int b = gm >> 11, l = gm & 2047;
                    O[((size_t)(b * 16 + h) * 64 + d) * 2048 + l] =
                        f2bf(acc[mi][ni][r] + bval);
                }
            }
        }
    }
}

// ---------------------------------------------------------------------------
// Kernel 2: flash attention (unchanged from R5/R6).
// ---------------------------------------------------------------------------
__global__ __launch_bounds__(256, 2)
void attn_kernel(const unsigned short* __restrict__ qh,
                 const unsigned short* __restrict__ kh,
                 const unsigned short* __restrict__ vt,
                 unsigned short* __restrict__ ao)
{
    __shared__ unsigned short Kl[2][64 * 64];
    __shared__ unsigned short Vl[2][64 * 64];
    __shared__ unsigned short Ps[8 * 1024];

    const int tid  = threadIdx.x;
    const int lane = tid & 63;
    const int w    = tid >> 6;
    const int l16  = lane & 15;
    const int quad = lane >> 4;
    const int qt   = blockIdx.x;
    const int bh   = blockIdx.y;

    const unsigned short* Qb = qh + (size_t)bh * 2048 * 64;
    const unsigned short* Kb = kh + (size_t)bh * 2048 * 64;
    const unsigned short* Vb = vt + (size_t)bh * 64 * 2048;

    const int qbase = qt * 128 + w * 32;

    const int rhi = lane >> 3;
    const int cg  = (lane & 7) ^ rhi;

    auto stage = [&](int s0t, int buf) {
#pragma unroll
        for (int r = 0; r < 2; r++) {
            int j = w * 2 + r;
            GLL(Kb + (size_t)(s0t + j * 8 + rhi) * 64 + cg * 8, &Kl[buf][j * 512]);
            GLL(Vb + (size_t)(j * 8 + rhi) * 2048 + s0t + cg * 8, &Vl[buf][j * 512]);
        }
    };

    bf16x8 qf[2][2];
#pragma unroll
    for (int qg = 0; qg < 2; qg++)
#pragma unroll
        for (int ks = 0; ks < 2; ks++)
            qf[qg][ks] = *(const bf16x8*)(Qb +
                (size_t)(qbase + qg * 16 + l16) * 64 + ks * 32 + quad * 8);

    f32x4 oacc[2][4];
#pragma unroll
    for (int qg = 0; qg < 2; qg++)
#pragma unroll
        for (int di = 0; di < 4; di++) {
            f32x4 zv = {0.0f, 0.0f, 0.0f, 0.0f};
            oacc[qg][di] = zv;
        }
    float l_[2] = {0.0f, 0.0f};

    unsigned short* Pw0 = Ps + (w * 2 + 0) * 1024;
    unsigned short* Pw1 = Ps + (w * 2 + 1) * 1024;

    const int c0 = (quad ^ (l16 & 7)) * 8;
    const int c1 = c0 ^ 32;

    stage(0, 0);
    __syncthreads();

    int buf = 0;
    for (int s0 = 0; s0 < 2048; s0 += 64) {
        if (s0 + 64 < 2048) stage(s0 + 64, buf ^ 1);

        const unsigned short* Kc = &Kl[buf][0];
        const unsigned short* Vc = &Vl[buf][0];

        bf16x8 kf[4][2], vf[4][2];
#pragma unroll
        for (int si = 0; si < 4; si++) {
            const unsigned short* kp = Kc + (si * 16 + l16) * 64;
            kf[si][0] = *(const bf16x8*)(kp + c0);
            kf[si][1] = *(const bf16x8*)(kp + c1);
        }
#pragma unroll
        for (int di = 0; di < 4; di++) {
            const unsigned short* vp = Vc + (di * 16 + l16) * 64;
            vf[di][0] = *(const bf16x8*)(vp + c0);
            vf[di][1] = *(const bf16x8*)(vp + c1);
        }

        f32x4 sacc[2][4];
#pragma unroll
        for (int qg = 0; qg < 2; qg++)
#pragma unroll
            for (int si = 0; si < 4; si++) {
                f32x4 sv = {-16.0f, -16.0f, -16.0f, -16.0f};
                sacc[qg][si] = sv;
            }
#pragma unroll
        for (int si = 0; si < 4; si++) {
            sacc[0][si] = MFMA16(kf[si][0], qf[0][0], sacc[0][si]);
            sacc[1][si] = MFMA16(kf[si][0], qf[1][0], sacc[1][si]);
            sacc[0][si] = MFMA16(kf[si][1], qf[0][1], sacc[0][si]);
            sacc[1][si] = MFMA16(kf[si][1], qf[1][1], sacc[1][si]);
        }

#pragma unroll
        for (int qg = 0; qg < 2; qg++) {
            float sum = 0.0f;
#pragma unroll
            for (int si = 0; si < 4; si++)
#pragma unroll
                for (int r = 0; r < 4; r++) {
                    float p = exp2f(sacc[qg][si][r]);
                    sacc[qg][si][r] = p;
                    sum += p;
                }
            l_[qg] += sum;
        }

#pragma unroll
        for (int si = 0; si < 4; si++) {
            int sc    = si >> 1;
            int quadp = (si & 1) * 2 + (quad >> 1);
            int off   = (sc * 64 + quadp * 16 + l16) * 8 + (quad & 1) * 4;
            u32x2 dw0, dw1;
            dw0[0] = pack2bf_fast(sacc[0][si][0], sacc[0][si][1]);
            dw0[1] = pack2bf_fast(sacc[0][si][2], sacc[0][si][3]);
            dw1[0] = pack2bf_fast(sacc[1][si][0], sacc[1][si][1]);
            dw1[1] = pack2bf_fast(sacc[1][si][2], sacc[1][si][3]);
            *(u32x2*)(Pw0 + off) = dw0;
            *(u32x2*)(Pw1 + off) = dw1;
        }

#pragma unroll
        for (int sc = 0; sc < 2; sc++) {
            bf16x8 pf0 = *(const bf16x8*)(Pw0 + (sc * 64 + lane) * 8);
            bf16x8 pf1 = *(const bf16x8*)(Pw1 + (sc * 64 + lane) * 8);
#pragma unroll
            for (int di = 0; di < 4; di++) {
                oacc[0][di] = MFMA16(vf[di][sc], pf0, oacc[0][di]);
                oacc[1][di] = MFMA16(vf[di][sc], pf1, oacc[1][di]);
            }
        }

        __syncthreads();
        buf ^= 1;
    }

    const int b = bh >> 4, h = bh & 15;
#pragma unroll
    for (int qg = 0; qg < 2; qg++) {
        float lt = l_[qg];
        lt += __shfl_xor(lt, 16, 64);
        lt += __shfl_xor(lt, 32, 64);
        float inv = 1.0f / lt;
        int q16 = qbase + qg * 16 + l16;
#pragma unroll
        for (int di = 0; di < 4; di++) {
            u16x4 pk;
#pragma unroll
            for (int r = 0; r < 4; r++) pk[r] = f2bf(oacc[qg][di][r] * inv);
            *(u16x4*)(ao + (size_t)(b * 2048 + q16) * 1024 +
                      h * 64 + di * 16 + quad * 4) = pk;
        }
    }
}

// ---------------------------------------------------------------------------
// Kernel 3 (path A): output projection, all-bf16, 64x128 tiles -> 512 blocks
// (R6 had 256 blocks = 1/CU: no co-resident overlap partner).
// Wave w owns 32(m) x 64(n): acc[2][4].
// ---------------------------------------------------------------------------
__global__ __launch_bounds__(256, 4)
void proj_out_bf16_kernel(const unsigned short* __restrict__ A,   // [4096][1024]
                          const unsigned short* __restrict__ Wb,  // [1024][1024] bf16
                          const float* __restrict__ bias,
                          float* __restrict__ out)
{
    __shared__ unsigned short As[64 * 32];   // 4 KB
    __shared__ unsigned short Bs[128 * 32];  // 8 KB

    const int tid  = threadIdx.x;
    const int lane = tid & 63;
    const int w    = tid >> 6;
    const int l16  = lane & 15;
    const int quad = lane >> 4;
    const int wm   = (w >> 1) * 32;
    const int wn   = (w & 1) * 64;
    const int m0   = blockIdx.y * 64;
    const int n0   = blockIdx.x * 128;

    const int rhi = lane >> 2;
    const int cg  = (lane & 3) ^ (rhi & 3);

    f32x4 acc[2][4];
#pragma unroll
    for (int i = 0; i < 2; i++)
#pragma unroll
        for (int j = 0; j < 4; j++) {
            f32x4 zv = {0.0f, 0.0f, 0.0f, 0.0f};
            acc[i][j] = zv;
        }

    const int sl = (quad ^ (l16 & 3)) * 8;

    for (int k0 = 0; k0 < 1024; k0 += 32) {
        GLL(A + (size_t)(m0 + w * 16 + rhi) * 1024 + k0 + cg * 8, &As[w * 512]);
#pragma unroll
        for (int r = 0; r < 2; r++) {
            int j = w * 2 + r;
            GLL(Wb + (size_t)(n0 + j * 16 + rhi) * 1024 + k0 + cg * 8, &Bs[j * 512]);
        }
        __syncthreads();

        bf16x8 af[2], bfr[4];
#pragma unroll
        for (int mi = 0; mi < 2; mi++)
            af[mi] = *(const bf16x8*)(&As[(wm + mi * 16 + l16) * 32 + sl]);
#pragma unroll
        for (int ni = 0; ni < 4; ni++)
            bfr[ni] = *(const bf16x8*)(&Bs[(wn + ni * 16 + l16) * 32 + sl]);
#pragma unroll
        for (int mi = 0; mi < 2; mi++)
#pragma unroll
            for (int ni = 0; ni < 4; ni++)
                acc[mi][ni] = MFMA16(af[mi], bfr[ni], acc[mi][ni]);
        __syncthreads();
    }

#pragma unroll
    for (int ni = 0; ni < 4; ni++) {
        int gn = n0 + wn + ni * 16 + l16;
        float bval = bias[gn];
#pragma unroll
        for (int mi = 0; mi < 2; mi++) {
#pragma unroll
            for (int r = 0; r < 4; r++) {
                int gm = m0 + wm + mi * 16 + quad * 4 + r;
                out[(size_t)gm * 1024 + gn] = acc[mi][ni][r] + bval;
            }
        }
    }
}

// ===========================================================================
// Path B fallback (ws < 64 MB): exact R6 kernels.
// ===========================================================================
__global__ __launch_bounds__(256, 2)
void proj_qkv_kernel(const float* __restrict__ Xq, const float* __restrict__ Xk,
                     const float* __restrict__ Xv,
                     const float* __restrict__ Wq, const float* __restrict__ Wk,
                     const float* __restrict__ Wv,
                     const float* __restrict__ bq, const float* __restrict__ bk,
                     const float* __restrict__ bv,
                     unsigned short* __restrict__ qh, unsigned short* __restrict__ kh,
                     unsigned short* __restrict__ vt)
{
    const int z = blockIdx.z;
    const float* X    = (z == 0) ? Xq : (z == 1) ? Xk : Xv;
    const float* W    = (z == 0) ? Wq : (z == 1) ? Wk : Wv;
    const float* bias = (z == 0) ? bq : (z == 1) ? bk : bv;
    unsigned short* O = (z == 0) ? qh : (z == 1) ? kh : vt;
    const float scale = (z == 0) ? 0.18033688011112042f : 1.0f;

    __shared__ float Af[128 * 32];
    __shared__ float Bf[128 * 32];

    const int tid  = threadIdx.x;
    const int lane = tid & 63;
    const int w    = tid >> 6;
    const int l16  = lane & 15;
    const int quad = lane >> 4;
    const int wm   = (w >> 1) * 64;
    const int wn   = (w & 1) * 64;
    const int m0   = blockIdx.y * 128;
    const int n0   = blockIdx.x * 128;

    const int rhi = lane >> 3;
    const int cg  = (lane & 7) ^ rhi;

    f32x4 acc[4][4];
#pragma unroll
    for (int i = 0; i < 4; i++)
#pragma unroll
        for (int j = 0; j < 4; j++) {
            f32x4 zv = {0.0f, 0.0f, 0.0f, 0.0f};
            acc[i][j] = zv;
        }

    const int sA = (2 * quad) ^ (l16 & 7);

    for (int k0 = 0; k0 < 1024; k0 += 32) {
#pragma unroll
        for (int r = 0; r < 4; r++) {
            int j = w * 4 + r;
            GLL(X + (size_t)(m0 + j * 8 + rhi) * 1024 + k0 + cg * 4, &Af[j * 8 * 32]);
            GLL(W + (size_t)(n0 + j * 8 + rhi) * 1024 + k0 + cg * 4, &Bf[j * 8 * 32]);
        }
        __syncthreads();

        bf16x8 af[4], bfr[4];
#pragma unroll
        for (int mi = 0; mi < 4; mi++) {
            const float* p = &Af[(wm + mi * 16 + l16) * 32];
            f32x4 ca = *(const f32x4*)(p + sA * 4);
            f32x4 cb = *(const f32x4*)(p + (sA ^ 1) * 4);
            af[mi] = cvt8(ca, cb);
        }
#pragma unroll
        for (int ni = 0; ni < 4; ni++) {
            const float* p = &Bf[(wn + ni * 16 + l16) * 32];
            f32x4 ca = *(const f32x4*)(p + sA * 4);
            f32x4 cb = *(const f32x4*)(p + (sA ^ 1) * 4);
            bfr[ni] = cvt8(ca, cb);
        }
        if (z != 2) {
#pragma unroll
            for (int mi = 0; mi < 4; mi++)
#pragma unroll
                for (int ni = 0; ni < 4; ni++)
                    acc[mi][ni] = MFMA16(af[mi], bfr[ni], acc[mi][ni]);
        } else {
#pragma unroll
            for (int mi = 0; mi < 4; mi++)
#pragma unroll
                for (int ni = 0; ni < 4; ni++)
                    acc[mi][ni] = MFMA16(bfr[ni], af[mi], acc[mi][ni]);
        }
        __syncthreads();
    }

    if (z != 2) {
#pragma unroll
        for (int ni = 0; ni < 4; ni++) {
            int gn = n0 + wn + ni * 16 + l16;
            float bval = bias[gn];
            int h = gn >> 6, d = gn & 63;
#pragma unroll
            for (int mi = 0; mi < 4; mi++) {
#pragma unroll
                for (int r = 0; r < 4; r++) {
                    int gm = m0 + wm + mi * 16 + quad * 4 + r;
                    int b = gm >> 11, l = gm & 2047;
                    float val = (acc[mi][ni][r] + bval) * scale;
                    O[(((size_t)(b * 16 + h) * 2048 + l) * 64) + d] = f2bf(val);
                }
            }
        }
    } else {
#pragma unroll
        for (int ni = 0; ni < 4; ni++) {
#pragma unroll
            for (int r = 0; r < 4; r++) {
                int gn = n0 + wn + ni * 16 + quad * 4 + r;
                float bval = bias[gn];
                int h = gn >> 6, d = gn & 63;
#pragma unroll
                for (int mi = 0; mi < 4; mi++) {
                    int gm = m0 + wm + mi * 16 + l16;
                    int b = gm >> 11, l = gm & 2047;
                    O[((size_t)(b * 16 + h) * 64 + d) * 2048 + l] =
                        f2bf(acc[mi][ni][r] + bval);
                }
            }
        }
    }
}

__global__ __launch_bounds__(256, 2)
void proj_out_kernel(const unsigned short* __restrict__ A,
                     const float* __restrict__ W,
                     const float* __restrict__ bias,
                     float* __restrict__ out)
{
    __shared__ unsigned short As[128 * 32];
    __shared__ float Bf[128 * 32];

    const int tid  = threadIdx.x;
    const int lane = tid & 63;
    const int w    = tid >> 6;
    const int l16  = lane & 15;
    const int quad = lane >> 4;
    const int wm   = (w >> 1) * 64;
    const int wn   = (w & 1) * 64;
    const int m0   = blockIdx.y * 128;
    const int n0   = blockIdx.x * 128;

    const int rhiA = lane >> 2;
    const int cgA  = (lane & 3) ^ (rhiA & 3);
    const int rhiB = lane >> 3;
    const int cgB  = (lane & 7) ^ rhiB;

    f32x4 acc[4][4];
#pragma unroll
    for (int i = 0; i < 4; i++)
#pragma unroll
        for (int j = 0; j < 4; j++) {
            f32x4 zv = {0.0f, 0.0f, 0.0f, 0.0f};
            acc[i][j] = zv;
        }

    const int sB  = (2 * quad) ^ (l16 & 7);
    const int sAq = quad ^ (l16 & 3);

    for (int k0 = 0; k0 < 1024; k0 += 32) {
#pragma unroll
        for (int r = 0; r < 2; r++) {
            int j = w * 2 + r;
            GLL(A + (size_t)(m0 + j * 16 + rhiA) * 1024 + k0 + cgA * 8, &As[j * 16 * 32]);
        }
#pragma unroll
        for (int r = 0; r < 4; r++) {
            int j = w * 4 + r;
            GLL(W + (size_t)(n0 + j * 8 + rhiB) * 1024 + k0 + cgB * 4, &Bf[j * 8 * 32]);
        }
        __syncthreads();

        bf16x8 af[4], bfr[4];
#pragma unroll
        for (int mi = 0; mi < 4; mi++)
            af[mi] = *(const bf16x8*)(&As[(wm + mi * 16 + l16) * 32 + sAq * 8]);
#pragma unroll
        for (int ni = 0; ni < 4; ni++) {
            const float* p = &Bf[(wn + ni * 16 + l16) * 32];
            f32x4 cb0 = *(const f32x4*)(p + sB * 4);
            f32x4 cb1 = *(const f32x4*)(p + (sB ^ 1) * 4);
            bfr[ni] = cvt8(cb0, cb1);
        }
#pragma unroll
        for (int mi = 0; mi < 4; mi++)
#pragma unroll
            for (int ni = 0; ni < 4; ni++)
                acc[mi][ni] = MFMA16(af[mi], bfr[ni], acc[mi][ni]);
        __syncthreads();
    }

#pragma unroll
    for (int ni = 0; ni < 4; ni++) {
        int gn = n0 + wn + ni * 16 + l16;
        float bval = bias[gn];
#pragma unroll
        for (int mi = 0; mi < 4; mi++) {
#pragma unroll
            for (int r = 0; r < 4; r++) {
                int gm = m0 + wm + mi * 16 + quad * 4 + r;
                out[(size_t)gm * 1024 + gn] = acc[mi][ni][r] + bval;
            }
        }
    }
}

// ---------------------------------------------------------------------------
extern "C" void kernel_launch(void* const* d_in, const int* in_sizes, int n_in,
                              void* d_out, int out_size, void* d_ws, size_t ws_size,
                              hipStream_t stream)
{
    const float* query = (const float*)d_in[0];
    const float* key   = (const float*)d_in[1];
    const float* value = (const float*)d_in[2];
    const float* Wq    = (const float*)d_in[3];
    const float* bq    = (const float*)d_in[4];
    const float* Wk    = (const float*)d_in[5];
    const float* bk    = (const float*)d_in[6];
    const float* Wv    = (const float*)d_in[7];
    const float* bv    = (const float*)d_in[8];
    const float* Wo    = (const float*)d_in[9];
    const float* bo    = (const float*)d_in[10];

    unsigned short* qh = (unsigned short*)d_ws;   // 4M ushorts each
    unsigned short* kh = qh + 4194304;
    unsigned short* vt = kh + 4194304;
    unsigned short* ao = vt + 4194304;
    float* out = (float*)d_out;

    if (ws_size >= (size_t)64 * 1024 * 1024) {
        unsigned short* xbf = ao + 4194304;       // 12M ushorts (q,k,v bf16)
        unsigned short* wbf = xbf + 12582912;     // 4M ushorts (Wq,Wk,Wv,Wo)
        cvt_kernel<<<dim3(256, 7), 256, 0, stream>>>(
            query, key, value, Wq, Wk, Wv, Wo, xbf, wbf);
        proj_qkv_bf16_kernel<<<dim3(8, 32, 3), 256, 0, stream>>>(
            xbf, wbf, bq, bk, bv, qh, kh, vt);
        attn_kernel<<<dim3(16, 32), 256, 0, stream>>>(qh, kh, vt, ao);
        proj_out_bf16_kernel<<<dim3(8, 64), 256, 0, stream>>>(
            ao, wbf + 3 * 1048576, bo, out);
    } else {
        proj_qkv_kernel<<<dim3(8, 32, 3), 256, 0, stream>>>(
            query, key, value, Wq, Wk, Wv, bq, bk, bv, qh, kh, vt);
        attn_kernel<<<dim3(16, 32), 256, 0, stream>>>(qh, kh, vt, ao);
        proj_out_kernel<<<dim3(8, 32), 256, 0, stream>>>(ao, Wo, bo, out);
    }
}

// Round 8
// 308.529 us; speedup vs baseline: 1.0038x; 1.0038x over previous
//
#include <hip/hip_runtime.h>
#include <math.h>

// MultiheadAttention: B=2, T=S=2048, C=1024, H=16, D=64
// ws layout (ushort units), path A (ws >= 64MB):
//   qh[4M] kh[4M] vt[4M] ao[4M] xbf[12M] wbf[4M]  = 64 MB
// qh/kh: [B*H][L][D]; vt: [B*H][D][S]; qh pre-scaled by log2(e)/sqrt(D).
// Path B (fallback, ws < 64MB): R6 kernels (fp32 LDS staging).

typedef __attribute__((ext_vector_type(4))) float f32x4;
typedef __attribute__((ext_vector_type(8))) __bf16 bf16x8;
typedef __attribute__((ext_vector_type(4))) unsigned int u32x4;
typedef __attribute__((ext_vector_type(2))) unsigned int u32x2;
typedef __attribute__((ext_vector_type(4))) unsigned short u16x4;

#define MFMA16(a, b, c) __builtin_amdgcn_mfma_f32_16x16x32_bf16(a, b, c, 0, 0, 0)

static __device__ __forceinline__ unsigned short f2bf(float f) {
    __bf16 h = (__bf16)f;
    return __builtin_bit_cast(unsigned short, h);
}
static __device__ __forceinline__ unsigned int pack2bf_fast(float a, float b) {
    unsigned int ua = __builtin_bit_cast(unsigned int, a) + 0x8000u;
    unsigned int ub = __builtin_bit_cast(unsigned int, b) + 0x8000u;
    return (ua >> 16) | (ub & 0xffff0000u);
}
static __device__ __forceinline__ bf16x8 cvt8(f32x4 a, f32x4 b) {
    bf16x8 t;
#pragma unroll
    for (int e = 0; e < 4; e++) { t[e] = (__bf16)a[e]; t[e + 4] = (__bf16)b[e]; }
    return t;
}

#define GLL(gptr, lptr) \
    __builtin_amdgcn_global_load_lds( \
        (const __attribute__((address_space(1))) unsigned int*)(gptr), \
        (__attribute__((address_space(3))) unsigned int*)(lptr), 16, 0, 0)

// ---------------------------------------------------------------------------
// Kernel 0 (path A): fp32 -> bf16 pre-convert (nontemporal fp32 reads: the
// fp32 originals are dead after this — keep them out of L2/LLC).
// ---------------------------------------------------------------------------
__global__ __launch_bounds__(256)
void cvt_kernel(const float* __restrict__ xq, const float* __restrict__ xk,
                const float* __restrict__ xv,
                const float* __restrict__ wq, const float* __restrict__ wk,
                const float* __restrict__ wv, const float* __restrict__ wo,
                unsigned short* __restrict__ xbf, unsigned short* __restrict__ wbf)
{
    const int t = blockIdx.y;  // 0..6
    const float* src;
    unsigned short* dst;
    int n;
    if (t < 3) {
        src = (t == 0) ? xq : (t == 1) ? xk : xv;
        dst = xbf + (size_t)t * 4194304;
        n = 4194304;
    } else {
        int u = t - 3;
        src = (u == 0) ? wq : (u == 1) ? wk : (u == 2) ? wv : wo;
        dst = wbf + (size_t)u * 1048576;
        n = 1048576;
    }
    for (int i = (blockIdx.x * 256 + threadIdx.x) * 4; i < n; i += gridDim.x * 1024) {
        f32x4 x = __builtin_nontemporal_load((const f32x4*)(src + i));
        u16x4 h;
#pragma unroll
        for (int e = 0; e < 4; e++) h[e] = f2bf(x[e]);
        *(u16x4*)(dst + i) = h;
    }
}

// ---------------------------------------------------------------------------
// Kernel 1 (path A): QKV projections, pure bf16 GEMM.
// R8: coalesced epilogue — acc is scattered into an LDS image of the output
// slab (bf16, bias/scale applied), then written with cooperative u32x4
// stores (consecutive lanes -> consecutive 16 B). This guarantees every
// 128-B output line is produced by one wave in one pass — kills the R7
// partial-line RMW write inflation (WRITE_SIZE 257 MB for 24 MB of output).
// ---------------------------------------------------------------------------
__global__ __launch_bounds__(256, 3)
void proj_qkv_bf16_kernel(const unsigned short* __restrict__ xbf,
                          const unsigned short* __restrict__ wbf,
                          const float* __restrict__ bq, const float* __restrict__ bk,
                          const float* __restrict__ bv,
                          unsigned short* __restrict__ qh, unsigned short* __restrict__ kh,
                          unsigned short* __restrict__ vt)
{
    const int z = blockIdx.z;
    const unsigned short* X = xbf + (size_t)z * 4194304;
    const unsigned short* W = wbf + (size_t)z * 1048576;
    const float* bias = (z == 0) ? bq : (z == 1) ? bk : bv;
    unsigned short* O = (z == 0) ? qh : (z == 1) ? kh : vt;
    const float scale = (z == 0) ? 0.18033688011112042f : 1.0f;

    // staging (8192 ushorts) and epilogue image (18432 ushorts) share Sh
    __shared__ unsigned short Sh[18432];
    unsigned short* As = Sh;
    unsigned short* Bs = Sh + 4096;

    const int tid  = threadIdx.x;
    const int lane = tid & 63;
    const int w    = tid >> 6;
    const int l16  = lane & 15;
    const int quad = lane >> 4;
    const int wm   = (w >> 1) * 64;
    const int wn   = (w & 1) * 64;
    const int m0   = blockIdx.y * 128;
    const int n0   = blockIdx.x * 128;

    const int rhi = lane >> 2;
    const int cg  = (lane & 3) ^ (rhi & 3);

    f32x4 acc[4][4];
#pragma unroll
    for (int i = 0; i < 4; i++)
#pragma unroll
        for (int j = 0; j < 4; j++) {
            f32x4 zv = {0.0f, 0.0f, 0.0f, 0.0f};
            acc[i][j] = zv;
        }

    const int sl = (quad ^ (l16 & 3)) * 8;

    for (int k0 = 0; k0 < 1024; k0 += 32) {
#pragma unroll
        for (int r = 0; r < 2; r++) {
            int j = w * 2 + r;
            GLL(X + (size_t)(m0 + j * 16 + rhi) * 1024 + k0 + cg * 8, &As[j * 512]);
            GLL(W + (size_t)(n0 + j * 16 + rhi) * 1024 + k0 + cg * 8, &Bs[j * 512]);
        }
        __syncthreads();

        bf16x8 af[4], bfr[4];
#pragma unroll
        for (int mi = 0; mi < 4; mi++)
            af[mi] = *(const bf16x8*)(&As[(wm + mi * 16 + l16) * 32 + sl]);
#pragma unroll
        for (int ni = 0; ni < 4; ni++)
            bfr[ni] = *(const bf16x8*)(&Bs[(wn + ni * 16 + l16) * 32 + sl]);
        if (z != 2) {
#pragma unroll
            for (int mi = 0; mi < 4; mi++)
#pragma unroll
                for (int ni = 0; ni < 4; ni++)
                    acc[mi][ni] = MFMA16(af[mi], bfr[ni], acc[mi][ni]);
        } else {
#pragma unroll
            for (int mi = 0; mi < 4; mi++)
#pragma unroll
                for (int ni = 0; ni < 4; ni++)
                    acc[mi][ni] = MFMA16(bfr[ni], af[mi], acc[mi][ni]);
        }
        __syncthreads();
    }

    const int b  = m0 >> 11;          // batch from token tile
    const int h0 = (n0 >> 6) & 15;    // first head of this n-tile
    const int l0 = m0 & 2047;

    if (z != 2) {
        // LDS image: [slab(h) 0..1][l 0..127] rows of 64 d, stride 72
#pragma unroll
        for (int ni = 0; ni < 4; ni++) {
            int gn = wn + ni * 16 + l16;         // block-local channel
            float bval = bias[n0 + gn];
            int slab = gn >> 6, d = gn & 63;
#pragma unroll
            for (int mi = 0; mi < 4; mi++)
#pragma unroll
                for (int r = 0; r < 4; r++) {
                    int l = wm + mi * 16 + quad * 4 + r;
                    Sh[(slab * 128 + l) * 72 + d] =
                        f2bf((acc[mi][ni][r] + bval) * scale);
                }
        }
        __syncthreads();
        // cooperative store: slab = contiguous 16 KB run in qh/kh
        unsigned short* dst0 = O + ((size_t)(b * 16 + h0) * 2048 + l0) * 64;
#pragma unroll
        for (int round = 0; round < 8; round++) {
            int f = round * 2048 + tid * 8;      // 0..16383
            int slab = f >> 13, rem = f & 8191;
            int l = rem >> 6, d = rem & 63;
            u32x4 v = *(const u32x4*)(&Sh[(slab * 128 + l) * 72 + d]);
            *(u32x4*)(dst0 + (size_t)slab * (2048 * 64) + rem) = v;
        }
    } else {
        // LDS image: [slab(h) 0..1][d 0..63] rows of 128 l, stride 144
#pragma unroll
        for (int ni = 0; ni < 4; ni++)
#pragma unroll
            for (int r = 0; r < 4; r++) {
                int gn = wn + ni * 16 + quad * 4 + r;  // block-local channel
                float bval = bias[n0 + gn];
                int slab = gn >> 6, d = gn & 63;
#pragma unroll
                for (int mi = 0; mi < 4; mi++) {
                    int col = wm + mi * 16 + l16;
                    Sh[(slab * 64 + d) * 144 + col] = f2bf(acc[mi][ni][r] + bval);
                }
            }
        __syncthreads();
        // cooperative store: each (h,d) row -> 256 B contiguous chunk of vt
#pragma unroll
        for (int round = 0; round < 8; round++) {
            int f = round * 2048 + tid * 8;
            int row = f >> 7, lcol = f & 127;    // row = slab*64 + d
            u32x4 v = *(const u32x4*)(&Sh[row * 144 + lcol]);
            *(u32x4*)(O + ((size_t)(b * 16 + h0) * 64 + row) * 2048 + l0 + lcol) = v;
        }
    }
}

// ---------------------------------------------------------------------------
// Kernel 2: flash attention (unchanged from R5/R6/R7).
// ---------------------------------------------------------------------------
__global__ __launch_bounds__(256, 2)
void attn_kernel(const unsigned short* __restrict__ qh,
                 const unsigned short* __restrict__ kh,
                 const unsigned short* __restrict__ vt,
                 unsigned short* __restrict__ ao)
{
    __shared__ unsigned short Kl[2][64 * 64];
    __shared__ unsigned short Vl[2][64 * 64];
    __shared__ unsigned short Ps[8 * 1024];

    const int tid  = threadIdx.x;
    const int lane = tid & 63;
    const int w    = tid >> 6;
    const int l16  = lane & 15;
    const int quad = lane >> 4;
    const int qt   = blockIdx.x;
    const int bh   = blockIdx.y;

    const unsigned short* Qb = qh + (size_t)bh * 2048 * 64;
    const unsigned short* Kb = kh + (size_t)bh * 2048 * 64;
    const unsigned short* Vb = vt + (size_t)bh * 64 * 2048;

    const int qbase = qt * 128 + w * 32;

    const int rhi = lane >> 3;
    const int cg  = (lane & 7) ^ rhi;

    auto stage = [&](int s0t, int buf) {
#pragma unroll
        for (int r = 0; r < 2; r++) {
            int j = w * 2 + r;
            GLL(Kb + (size_t)(s0t + j * 8 + rhi) * 64 + cg * 8, &Kl[buf][j * 512]);
            GLL(Vb + (size_t)(j * 8 + rhi) * 2048 + s0t + cg * 8, &Vl[buf][j * 512]);
        }
    };

    bf16x8 qf[2][2];
#pragma unroll
    for (int qg = 0; qg < 2; qg++)
#pragma unroll
        for (int ks = 0; ks < 2; ks++)
            qf[qg][ks] = *(const bf16x8*)(Qb +
                (size_t)(qbase + qg * 16 + l16) * 64 + ks * 32 + quad * 8);

    f32x4 oacc[2][4];
#pragma unroll
    for (int qg = 0; qg < 2; qg++)
#pragma unroll
        for (int di = 0; di < 4; di++) {
            f32x4 zv = {0.0f, 0.0f, 0.0f, 0.0f};
            oacc[qg][di] = zv;
        }
    float l_[2] = {0.0f, 0.0f};

    unsigned short* Pw0 = Ps + (w * 2 + 0) * 1024;
    unsigned short* Pw1 = Ps + (w * 2 + 1) * 1024;

    const int c0 = (quad ^ (l16 & 7)) * 8;
    const int c1 = c0 ^ 32;

    stage(0, 0);
    __syncthreads();

    int buf = 0;
    for (int s0 = 0; s0 < 2048; s0 += 64) {
        if (s0 + 64 < 2048) stage(s0 + 64, buf ^ 1);

        const unsigned short* Kc = &Kl[buf][0];
        const unsigned short* Vc = &Vl[buf][0];

        bf16x8 kf[4][2], vf[4][2];
#pragma unroll
        for (int si = 0; si < 4; si++) {
            const unsigned short* kp = Kc + (si * 16 + l16) * 64;
            kf[si][0] = *(const bf16x8*)(kp + c0);
            kf[si][1] = *(const bf16x8*)(kp + c1);
        }
#pragma unroll
        for (int di = 0; di < 4; di++) {
            const unsigned short* vp = Vc + (di * 16 + l16) * 64;
            vf[di][0] = *(const bf16x8*)(vp + c0);
            vf[di][1] = *(const bf16x8*)(vp + c1);
        }

        f32x4 sacc[2][4];
#pragma unroll
        for (int qg = 0; qg < 2; qg++)
#pragma unroll
            for (int si = 0; si < 4; si++) {
                f32x4 sv = {-16.0f, -16.0f, -16.0f, -16.0f};
                sacc[qg][si] = sv;
            }
#pragma unroll
        for (int si = 0; si < 4; si++) {
            sacc[0][si] = MFMA16(kf[si][0], qf[0][0], sacc[0][si]);
            sacc[1][si] = MFMA16(kf[si][0], qf[1][0], sacc[1][si]);
            sacc[0][si] = MFMA16(kf[si][1], qf[0][1], sacc[0][si]);
            sacc[1][si] = MFMA16(kf[si][1], qf[1][1], sacc[1][si]);
        }

#pragma unroll
        for (int qg = 0; qg < 2; qg++) {
            float sum = 0.0f;
#pragma unroll
            for (int si = 0; si < 4; si++)
#pragma unroll
                for (int r = 0; r < 4; r++) {
                    float p = exp2f(sacc[qg][si][r]);
                    sacc[qg][si][r] = p;
                    sum += p;
                }
            l_[qg] += sum;
        }

#pragma unroll
        for (int si = 0; si < 4; si++) {
            int sc    = si >> 1;
            int quadp = (si & 1) * 2 + (quad >> 1);
            int off   = (sc * 64 + quadp * 16 + l16) * 8 + (quad & 1) * 4;
            u32x2 dw0, dw1;
            dw0[0] = pack2bf_fast(sacc[0][si][0], sacc[0][si][1]);
            dw0[1] = pack2bf_fast(sacc[0][si][2], sacc[0][si][3]);
            dw1[0] = pack2bf_fast(sacc[1][si][0], sacc[1][si][1]);
            dw1[1] = pack2bf_fast(sacc[1][si][2], sacc[1][si][3]);
            *(u32x2*)(Pw0 + off) = dw0;
            *(u32x2*)(Pw1 + off) = dw1;
        }

#pragma unroll
        for (int sc = 0; sc < 2; sc++) {
            bf16x8 pf0 = *(const bf16x8*)(Pw0 + (sc * 64 + lane) * 8);
            bf16x8 pf1 = *(const bf16x8*)(Pw1 + (sc * 64 + lane) * 8);
#pragma unroll
            for (int di = 0; di < 4; di++) {
                oacc[0][di] = MFMA16(vf[di][sc], pf0, oacc[0][di]);
                oacc[1][di] = MFMA16(vf[di][sc], pf1, oacc[1][di]);
            }
        }

        __syncthreads();
        buf ^= 1;
    }

    const int b = bh >> 4, h = bh & 15;
#pragma unroll
    for (int qg = 0; qg < 2; qg++) {
        float lt = l_[qg];
        lt += __shfl_xor(lt, 16, 64);
        lt += __shfl_xor(lt, 32, 64);
        float inv = 1.0f / lt;
        int q16 = qbase + qg * 16 + l16;
#pragma unroll
        for (int di = 0; di < 4; di++) {
            u16x4 pk;
#pragma unroll
            for (int r = 0; r < 4; r++) pk[r] = f2bf(oacc[qg][di][r] * inv);
            *(u16x4*)(ao + (size_t)(b * 2048 + q16) * 1024 +
                      h * 64 + di * 16 + quad * 4) = pk;
        }
    }
}

// ---------------------------------------------------------------------------
// Kernel 3 (path A): output projection, all-bf16, 64x128 tiles (512 blocks).
// ---------------------------------------------------------------------------
__global__ __launch_bounds__(256, 4)
void proj_out_bf16_kernel(const unsigned short* __restrict__ A,   // [4096][1024]
                          const unsigned short* __restrict__ Wb,  // [1024][1024] bf16
                          const float* __restrict__ bias,
                          float* __restrict__ out)
{
    __shared__ unsigned short As[64 * 32];
    __shared__ unsigned short Bs[128 * 32];

    const int tid  = threadIdx.x;
    const int lane = tid & 63;
    const int w    = tid >> 6;
    const int l16  = lane & 15;
    const int quad = lane >> 4;
    const int wm   = (w >> 1) * 32;
    const int wn   = (w & 1) * 64;
    const int m0   = blockIdx.y * 64;
    const int n0   = blockIdx.x * 128;

    const int rhi = lane >> 2;
    const int cg  = (lane & 3) ^ (rhi & 3);

    f32x4 acc[2][4];
#pragma unroll
    for (int i = 0; i < 2; i++)
#pragma unroll
        for (int j = 0; j < 4; j++) {
            f32x4 zv = {0.0f, 0.0f, 0.0f, 0.0f};
            acc[i][j] = zv;
        }

    const int sl = (quad ^ (l16 & 3)) * 8;

    for (int k0 = 0; k0 < 1024; k0 += 32) {
        GLL(A + (size_t)(m0 + w * 16 + rhi) * 1024 + k0 + cg * 8, &As[w * 512]);
#pragma unroll
        for (int r = 0; r < 2; r++) {
            int j = w * 2 + r;
            GLL(Wb + (size_t)(n0 + j * 16 + rhi) * 1024 + k0 + cg * 8, &Bs[j * 512]);
        }
        __syncthreads();

        bf16x8 af[2], bfr[4];
#pragma unroll
        for (int mi = 0; mi < 2; mi++)
            af[mi] = *(const bf16x8*)(&As[(wm + mi * 16 + l16) * 32 + sl]);
#pragma unroll
        for (int ni = 0; ni < 4; ni++)
            bfr[ni] = *(const bf16x8*)(&Bs[(wn + ni * 16 + l16) * 32 + sl]);
#pragma unroll
        for (int mi = 0; mi < 2; mi++)
#pragma unroll
            for (int ni = 0; ni < 4; ni++)
                acc[mi][ni] = MFMA16(af[mi], bfr[ni], acc[mi][ni]);
        __syncthreads();
    }

#pragma unroll
    for (int ni = 0; ni < 4; ni++) {
        int gn = n0 + wn + ni * 16 + l16;
        float bval = bias[gn];
#pragma unroll
        for (int mi = 0; mi < 2; mi++) {
#pragma unroll
            for (int r = 0; r < 4; r++) {
                int gm = m0 + wm + mi * 16 + quad * 4 + r;
                out[(size_t)gm * 1024 + gn] = acc[mi][ni][r] + bval;
            }
        }
    }
}

// ===========================================================================
// Path B fallback (ws < 64 MB): R6 kernels.
// ===========================================================================
__global__ __launch_bounds__(256, 2)
void proj_qkv_kernel(const float* __restrict__ Xq, const float* __restrict__ Xk,
                     const float* __restrict__ Xv,
                     const float* __restrict__ Wq, const float* __restrict__ Wk,
                     const float* __restrict__ Wv,
                     const float* __restrict__ bq, const float* __restrict__ bk,
                     const float* __restrict__ bv,
                     unsigned short* __restrict__ qh, unsigned short* __restrict__ kh,
                     unsigned short* __restrict__ vt)
{
    const int z = blockIdx.z;
    const float* X    = (z == 0) ? Xq : (z == 1) ? Xk : Xv;
    const float* W    = (z == 0) ? Wq : (z == 1) ? Wk : Wv;
    const float* bias = (z == 0) ? bq : (z == 1) ? bk : bv;
    unsigned short* O = (z == 0) ? qh : (z == 1) ? kh : vt;
    const float scale = (z == 0) ? 0.18033688011112042f : 1.0f;

    __shared__ float Af[128 * 32];
    __shared__ float Bf[128 * 32];

    const int tid  = threadIdx.x;
    const int lane = tid & 63;
    const int w    = tid >> 6;
    const int l16  = lane & 15;
    const int quad = lane >> 4;
    const int wm   = (w >> 1) * 64;
    const int wn   = (w & 1) * 64;
    const int m0   = blockIdx.y * 128;
    const int n0   = blockIdx.x * 128;

    const int rhi = lane >> 3;
    const int cg  = (lane & 7) ^ rhi;

    f32x4 acc[4][4];
#pragma unroll
    for (int i = 0; i < 4; i++)
#pragma unroll
        for (int j = 0; j < 4; j++) {
            f32x4 zv = {0.0f, 0.0f, 0.0f, 0.0f};
            acc[i][j] = zv;
        }

    const int sA = (2 * quad) ^ (l16 & 7);

    for (int k0 = 0; k0 < 1024; k0 += 32) {
#pragma unroll
        for (int r = 0; r < 4; r++) {
            int j = w * 4 + r;
            GLL(X + (size_t)(m0 + j * 8 + rhi) * 1024 + k0 + cg * 4, &Af[j * 8 * 32]);
            GLL(W + (size_t)(n0 + j * 8 + rhi) * 1024 + k0 + cg * 4, &Bf[j * 8 * 32]);
        }
        __syncthreads();

        bf16x8 af[4], bfr[4];
#pragma unroll
        for (int mi = 0; mi < 4; mi++) {
            const float* p = &Af[(wm + mi * 16 + l16) * 32];
            f32x4 ca = *(const f32x4*)(p + sA * 4);
            f32x4 cb = *(const f32x4*)(p + (sA ^ 1) * 4);
            af[mi] = cvt8(ca, cb);
        }
#pragma unroll
        for (int ni = 0; ni < 4; ni++) {
            const float* p = &Bf[(wn + ni * 16 + l16) * 32];
            f32x4 ca = *(const f32x4*)(p + sA * 4);
            f32x4 cb = *(const f32x4*)(p + (sA ^ 1) * 4);
            bfr[ni] = cvt8(ca, cb);
        }
        if (z != 2) {
#pragma unroll
            for (int mi = 0; mi < 4; mi++)
#pragma unroll
                for (int ni = 0; ni < 4; ni++)
                    acc[mi][ni] = MFMA16(af[mi], bfr[ni], acc[mi][ni]);
        } else {
#pragma unroll
            for (int mi = 0; mi < 4; mi++)
#pragma unroll
                for (int ni = 0; ni < 4; ni++)
                    acc[mi][ni] = MFMA16(bfr[ni], af[mi], acc[mi][ni]);
        }
        __syncthreads();
    }

    if (z != 2) {
#pragma unroll
        for (int ni = 0; ni < 4; ni++) {
            int gn = n0 + wn + ni * 16 + l16;
            float bval = bias[gn];
            int h = gn >> 6, d = gn & 63;
#pragma unroll
            for (int mi = 0; mi < 4; mi++) {
#pragma unroll
                for (int r = 0; r < 4; r++) {
                    int gm = m0 + wm + mi * 16 + quad * 4 + r;
                    int b = gm >> 11, l = gm & 2047;
                    float val = (acc[mi][ni][r] + bval) * scale;
                    O[(((size_t)(b * 16 + h) * 2048 + l) * 64) + d] = f2bf(val);
                }
            }
        }
    } else {
#pragma unroll
        for (int ni = 0; ni < 4; ni++) {
#pragma unroll
            for (int r = 0; r < 4; r++) {
                int gn = n0 + wn + ni * 16 + quad * 4 + r;
                float bval = bias[gn];
                int h = gn >> 6, d = gn & 63;
#pragma unroll
                for (int mi = 0; mi < 4; mi++) {
                    int gm = m0 + wm + mi * 16 + l16;
                    int b = gm >> 11, l = gm & 2047;
                    O[((size_t)(b * 16 + h) * 64 + d) * 2048 + l] =
                        f2bf(acc[mi][ni][r] + bval);
                }
            }
        }
    }
}

__global__ __launch_bounds__(256, 2)
void proj_out_kernel(const unsigned short* __restrict__ A,
                     const float* __restrict__ W,
                     const float* __restrict__ bias,
                     float* __restrict__ out)
{
    __shared__ unsigned short As[128 * 32];
    __shared__ float Bf[128 * 32];

    const int tid  = threadIdx.x;
    const int lane = tid & 63;
    const int w    = tid >> 6;
    const int l16  = lane & 15;
    const int quad = lane >> 4;
    const int wm   = (w >> 1) * 64;
    const int wn   = (w & 1) * 64;
    const int m0   = blockIdx.y * 128;
    const int n0   = blockIdx.x * 128;

    const int rhiA = lane >> 2;
    const int cgA  = (lane & 3) ^ (rhiA & 3);
    const int rhiB = lane >> 3;
    const int cgB  = (lane & 7) ^ rhiB;

    f32x4 acc[4][4];
#pragma unroll
    for (int i = 0; i < 4; i++)
#pragma unroll
        for (int j = 0; j < 4; j++) {
            f32x4 zv = {0.0f, 0.0f, 0.0f, 0.0f};
            acc[i][j] = zv;
        }

    const int sB  = (2 * quad) ^ (l16 & 7);
    const int sAq = quad ^ (l16 & 3);

    for (int k0 = 0; k0 < 1024; k0 += 32) {
#pragma unroll
        for (int r = 0; r < 2; r++) {
            int j = w * 2 + r;
            GLL(A + (size_t)(m0 + j * 16 + rhiA) * 1024 + k0 + cgA * 8, &As[j * 16 * 32]);
        }
#pragma unroll
        for (int r = 0; r < 4; r++) {
            int j = w * 4 + r;
            GLL(W + (size_t)(n0 + j * 8 + rhiB) * 1024 + k0 + cgB * 4, &Bf[j * 8 * 32]);
        }
        __syncthreads();

        bf16x8 af[4], bfr[4];
#pragma unroll
        for (int mi = 0; mi < 4; mi++)
            af[mi] = *(const bf16x8*)(&As[(wm + mi * 16 + l16) * 32 + sAq * 8]);
#pragma unroll
        for (int ni = 0; ni < 4; ni++) {
            const float* p = &Bf[(wn + ni * 16 + l16) * 32];
            f32x4 cb0 = *(const f32x4*)(p + sB * 4);
            f32x4 cb1 = *(const f32x4*)(p + (sB ^ 1) * 4);
            bfr[ni] = cvt8(cb0, cb1);
        }
#pragma unroll
        for (int mi = 0; mi < 4; mi++)
#pragma unroll
            for (int ni = 0; ni < 4; ni++)
                acc[mi][ni] = MFMA16(af[mi], bfr[ni], acc[mi][ni]);
        __syncthreads();
    }

#pragma unroll
    for (int ni = 0; ni < 4; ni++) {
        int gn = n0 + wn + ni * 16 + l16;
        float bval = bias[gn];
#pragma unroll
        for (int mi = 0; mi < 4; mi++) {
#pragma unroll
            for (int r = 0; r < 4; r++) {
                int gm = m0 + wm + mi * 16 + quad * 4 + r;
                out[(size_t)gm * 1024 + gn] = acc[mi][ni][r] + bval;
            }
        }
    }
}

// ---------------------------------------------------------------------------
extern "C" void kernel_launch(void* const* d_in, const int* in_sizes, int n_in,
                              void* d_out, int out_size, void* d_ws, size_t ws_size,
                              hipStream_t stream)
{
    const float* query = (const float*)d_in[0];
    const float* key   = (const float*)d_in[1];
    const float* value = (const float*)d_in[2];
    const float* Wq    = (const float*)d_in[3];
    const float* bq    = (const float*)d_in[4];
    const float* Wk    = (const float*)d_in[5];
    const float* bk    = (const float*)d_in[6];
    const float* Wv    = (const float*)d_in[7];
    const float* bv    = (const float*)d_in[8];
    const float* Wo    = (const float*)d_in[9];
    const float* bo    = (const float*)d_in[10];

    unsigned short* qh = (unsigned short*)d_ws;
    unsigned short* kh = qh + 4194304;
    unsigned short* vt = kh + 4194304;
    unsigned short* ao = vt + 4194304;
    float* out = (float*)d_out;

    if (ws_size >= (size_t)64 * 1024 * 1024) {
        unsigned short* xbf = ao + 4194304;
        unsigned short* wbf = xbf + 12582912;
        cvt_kernel<<<dim3(256, 7), 256, 0, stream>>>(
            query, key, value, Wq, Wk, Wv, Wo, xbf, wbf);
        proj_qkv_bf16_kernel<<<dim3(8, 32, 3), 256, 0, stream>>>(
            xbf, wbf, bq, bk, bv, qh, kh, vt);
        attn_kernel<<<dim3(16, 32), 256, 0, stream>>>(qh, kh, vt, ao);
        proj_out_bf16_kernel<<<dim3(8, 64), 256, 0, stream>>>(
            ao, wbf + 3 * 1048576, bo, out);
    } else {
        proj_qkv_kernel<<<dim3(8, 32, 3), 256, 0, stream>>>(
            query, key, value, Wq, Wk, Wv, bq, bk, bv, qh, kh, vt);
        attn_kernel<<<dim3(16, 32), 256, 0, stream>>>(qh, kh, vt, ao);
        proj_out_kernel<<<dim3(8, 32), 256, 0, stream>>>(ao, Wo, bo, out);
    }
}

// Round 9
// 288.248 us; speedup vs baseline: 1.0744x; 1.0704x over previous
//
#include <hip/hip_runtime.h>
#include <math.h>

// MultiheadAttention: B=2, T=S=2048, C=1024, H=16, D=64
// ws layout (bf16 as ushort): qh[4M] kh[4M] vt[4M] ao[4M] = 32 MB.
// qh/kh: [B*H][L][D]; vt: [B*H][D][S] (V stored transposed by proj_qkv).
// qh pre-scaled by log2(e)/sqrt(D) so attn softmax runs in exp2 domain.
// R9: reverted to fused fp32-staging projections (R7/R8 cvt-split produced
// 10x WRITE churn and was net slower); attn re-tiled 64q -> 4 blocks/CU.

typedef __attribute__((ext_vector_type(4))) float f32x4;
typedef __attribute__((ext_vector_type(8))) __bf16 bf16x8;
typedef __attribute__((ext_vector_type(4))) unsigned int u32x4;
typedef __attribute__((ext_vector_type(2))) unsigned int u32x2;
typedef __attribute__((ext_vector_type(4))) unsigned short u16x4;

#define MFMA16(a, b, c) __builtin_amdgcn_mfma_f32_16x16x32_bf16(a, b, c, 0, 0, 0)

static __device__ __forceinline__ unsigned short f2bf(float f) {
    __bf16 h = (__bf16)f;
    return __builtin_bit_cast(unsigned short, h);
}
static __device__ __forceinline__ unsigned int pack2bf_fast(float a, float b) {
    unsigned int ua = __builtin_bit_cast(unsigned int, a) + 0x8000u;
    unsigned int ub = __builtin_bit_cast(unsigned int, b) + 0x8000u;
    return (ua >> 16) | (ub & 0xffff0000u);
}
static __device__ __forceinline__ bf16x8 cvt8(f32x4 a, f32x4 b) {
    bf16x8 t;
#pragma unroll
    for (int e = 0; e < 4; e++) { t[e] = (__bf16)a[e]; t[e + 4] = (__bf16)b[e]; }
    return t;
}

#define GLL(gptr, lptr) \
    __builtin_amdgcn_global_load_lds( \
        (const __attribute__((address_space(1))) unsigned int*)(gptr), \
        (__attribute__((address_space(3))) unsigned int*)(lptr), 16, 0, 0)

// ---------------------------------------------------------------------------
// Kernel 1: QKV projections, fused fp32 GLL staging (R6, proven 91 us /
// WRITE_SIZE == output). fp32 -> bf16 conversion at fragment-read time.
// z=0 (Q, pre-scaled log2e/8), z=1 (K): out [B,H,L,D]. z=2 (V): out [B,H,D,S].
// ---------------------------------------------------------------------------
__global__ __launch_bounds__(256, 2)
void proj_qkv_kernel(const float* __restrict__ Xq, const float* __restrict__ Xk,
                     const float* __restrict__ Xv,
                     const float* __restrict__ Wq, const float* __restrict__ Wk,
                     const float* __restrict__ Wv,
                     const float* __restrict__ bq, const float* __restrict__ bk,
                     const float* __restrict__ bv,
                     unsigned short* __restrict__ qh, unsigned short* __restrict__ kh,
                     unsigned short* __restrict__ vt)
{
    const int z = blockIdx.z;
    const float* X    = (z == 0) ? Xq : (z == 1) ? Xk : Xv;
    const float* W    = (z == 0) ? Wq : (z == 1) ? Wk : Wv;
    const float* bias = (z == 0) ? bq : (z == 1) ? bk : bv;
    unsigned short* O = (z == 0) ? qh : (z == 1) ? kh : vt;
    const float scale = (z == 0) ? 0.18033688011112042f : 1.0f;

    __shared__ float Af[128 * 32];
    __shared__ float Bf[128 * 32];

    const int tid  = threadIdx.x;
    const int lane = tid & 63;
    const int w    = tid >> 6;
    const int l16  = lane & 15;
    const int quad = lane >> 4;
    const int wm   = (w >> 1) * 64;
    const int wn   = (w & 1) * 64;
    const int m0   = blockIdx.y * 128;
    const int n0   = blockIdx.x * 128;

    const int rhi = lane >> 3;
    const int cg  = (lane & 7) ^ rhi;

    f32x4 acc[4][4];
#pragma unroll
    for (int i = 0; i < 4; i++)
#pragma unroll
        for (int j = 0; j < 4; j++) {
            f32x4 zv = {0.0f, 0.0f, 0.0f, 0.0f};
            acc[i][j] = zv;
        }

    const int sA = (2 * quad) ^ (l16 & 7);

    for (int k0 = 0; k0 < 1024; k0 += 32) {
#pragma unroll
        for (int r = 0; r < 4; r++) {
            int j = w * 4 + r;
            GLL(X + (size_t)(m0 + j * 8 + rhi) * 1024 + k0 + cg * 4, &Af[j * 8 * 32]);
            GLL(W + (size_t)(n0 + j * 8 + rhi) * 1024 + k0 + cg * 4, &Bf[j * 8 * 32]);
        }
        __syncthreads();

        bf16x8 af[4], bfr[4];
#pragma unroll
        for (int mi = 0; mi < 4; mi++) {
            const float* p = &Af[(wm + mi * 16 + l16) * 32];
            f32x4 ca = *(const f32x4*)(p + sA * 4);
            f32x4 cb = *(const f32x4*)(p + (sA ^ 1) * 4);
            af[mi] = cvt8(ca, cb);
        }
#pragma unroll
        for (int ni = 0; ni < 4; ni++) {
            const float* p = &Bf[(wn + ni * 16 + l16) * 32];
            f32x4 ca = *(const f32x4*)(p + sA * 4);
            f32x4 cb = *(const f32x4*)(p + (sA ^ 1) * 4);
            bfr[ni] = cvt8(ca, cb);
        }
        if (z != 2) {
#pragma unroll
            for (int mi = 0; mi < 4; mi++)
#pragma unroll
                for (int ni = 0; ni < 4; ni++)
                    acc[mi][ni] = MFMA16(af[mi], bfr[ni], acc[mi][ni]);
        } else {
#pragma unroll
            for (int mi = 0; mi < 4; mi++)
#pragma unroll
                for (int ni = 0; ni < 4; ni++)
                    acc[mi][ni] = MFMA16(bfr[ni], af[mi], acc[mi][ni]);
        }
        __syncthreads();
    }

    if (z != 2) {
#pragma unroll
        for (int ni = 0; ni < 4; ni++) {
            int gn = n0 + wn + ni * 16 + l16;
            float bval = bias[gn];
            int h = gn >> 6, d = gn & 63;
#pragma unroll
            for (int mi = 0; mi < 4; mi++) {
#pragma unroll
                for (int r = 0; r < 4; r++) {
                    int gm = m0 + wm + mi * 16 + quad * 4 + r;
                    int b = gm >> 11, l = gm & 2047;
                    float val = (acc[mi][ni][r] + bval) * scale;
                    O[(((size_t)(b * 16 + h) * 2048 + l) * 64) + d] = f2bf(val);
                }
            }
        }
    } else {
#pragma unroll
        for (int ni = 0; ni < 4; ni++) {
#pragma unroll
            for (int r = 0; r < 4; r++) {
                int gn = n0 + wn + ni * 16 + quad * 4 + r;
                float bval = bias[gn];
                int h = gn >> 6, d = gn & 63;
#pragma unroll
                for (int mi = 0; mi < 4; mi++) {
                    int gm = m0 + wm + mi * 16 + l16;
                    int b = gm >> 11, l = gm & 2047;
                    O[((size_t)(b * 16 + h) * 64 + d) * 2048 + l] =
                        f2bf(acc[mi][ni][r] + bval);
                }
            }
        }
    }
}

// ---------------------------------------------------------------------------
// Kernel 2: flash attention. R9: 64-q blocks (grid 32x32 = 1024), LDS 40 KB
// (Kl 16 + Vl 16 + Ps 8) -> exactly 4 blocks/CU at launch_bounds(256,4):
// doubles resident waves vs R5-R8 (2/CU grid-limited), halving exposed
// barrier-drain per unit work. Wave owns 16 q; structure otherwise R5.
// ---------------------------------------------------------------------------
__global__ __launch_bounds__(256, 4)
void attn_kernel(const unsigned short* __restrict__ qh,
                 const unsigned short* __restrict__ kh,
                 const unsigned short* __restrict__ vt,
                 unsigned short* __restrict__ ao)
{
    __shared__ unsigned short Kl[2][64 * 64];  // [buf][s][d] chunk-swizzled
    __shared__ unsigned short Vl[2][64 * 64];  // [buf][d][s] chunk-swizzled
    __shared__ unsigned short Ps[4 * 1024];    // P round-trip, wave-private

    const int tid  = threadIdx.x;
    const int lane = tid & 63;
    const int w    = tid >> 6;
    const int l16  = lane & 15;
    const int quad = lane >> 4;
    const int qt   = blockIdx.x;  // 0..31
    const int bh   = blockIdx.y;  // 0..31

    const unsigned short* Qb = qh + (size_t)bh * 2048 * 64;
    const unsigned short* Kb = kh + (size_t)bh * 2048 * 64;
    const unsigned short* Vb = vt + (size_t)bh * 64 * 2048;

    const int qbase = qt * 64 + w * 16;

    const int rhi = lane >> 3;
    const int cg  = (lane & 7) ^ rhi;

    auto stage = [&](int s0t, int buf) {
#pragma unroll
        for (int r = 0; r < 2; r++) {
            int j = w * 2 + r;
            GLL(Kb + (size_t)(s0t + j * 8 + rhi) * 64 + cg * 8, &Kl[buf][j * 512]);
            GLL(Vb + (size_t)(j * 8 + rhi) * 2048 + s0t + cg * 8, &Vl[buf][j * 512]);
        }
    };

    // Q as B-operand: n=l16=q, k=quad*8+j=d. Loaded once.
    bf16x8 qf[2];
#pragma unroll
    for (int ks = 0; ks < 2; ks++)
        qf[ks] = *(const bf16x8*)(Qb +
            (size_t)(qbase + l16) * 64 + ks * 32 + quad * 8);

    f32x4 oacc[4];  // O^T: col=q(=l16), row=d=di*16+quad*4+r
#pragma unroll
    for (int di = 0; di < 4; di++) {
        f32x4 zv = {0.0f, 0.0f, 0.0f, 0.0f};
        oacc[di] = zv;
    }
    float l_ = 0.0f;

    unsigned short* Pw = Ps + w * 1024;

    const int c0 = (quad ^ (l16 & 7)) * 8;
    const int c1 = c0 ^ 32;

    stage(0, 0);
    __syncthreads();

    int buf = 0;
    for (int s0 = 0; s0 < 2048; s0 += 64) {
        if (s0 + 64 < 2048) stage(s0 + 64, buf ^ 1);

        const unsigned short* Kc = &Kl[buf][0];
        const unsigned short* Vc = &Vl[buf][0];

        bf16x8 kf[4][2], vf[4][2];
#pragma unroll
        for (int si = 0; si < 4; si++) {
            const unsigned short* kp = Kc + (si * 16 + l16) * 64;
            kf[si][0] = *(const bf16x8*)(kp + c0);
            kf[si][1] = *(const bf16x8*)(kp + c1);
        }
#pragma unroll
        for (int di = 0; di < 4; di++) {
            const unsigned short* vp = Vc + (di * 16 + l16) * 64;
            vf[di][0] = *(const bf16x8*)(vp + c0);
            vf[di][1] = *(const bf16x8*)(vp + c1);
        }

        // --- S^T = K Q^T; C init = -16 = the fixed softmax shift ---
        f32x4 sacc[4];
#pragma unroll
        for (int si = 0; si < 4; si++) {
            f32x4 sv = {-16.0f, -16.0f, -16.0f, -16.0f};
            sacc[si] = sv;
        }
#pragma unroll
        for (int si = 0; si < 4; si++) {
            sacc[si] = MFMA16(kf[si][0], qf[0], sacc[si]);
            sacc[si] = MFMA16(kf[si][1], qf[1], sacc[si]);
        }

        // --- fixed-shift softmax: p = exp2(s) (pre-shifted) ---
        float sum = 0.0f;
#pragma unroll
        for (int si = 0; si < 4; si++)
#pragma unroll
            for (int r = 0; r < 4; r++) {
                float p = exp2f(sacc[si][r]);
                sacc[si][r] = p;
                sum += p;
            }
        l_ += sum;

        // --- P^T C-layout -> B-frag order, wave-private LDS (no barrier) ---
#pragma unroll
        for (int si = 0; si < 4; si++) {
            int sc    = si >> 1;
            int quadp = (si & 1) * 2 + (quad >> 1);
            int off   = (sc * 64 + quadp * 16 + l16) * 8 + (quad & 1) * 4;
            u32x2 dw;
            dw[0] = pack2bf_fast(sacc[si][0], sacc[si][1]);
            dw[1] = pack2bf_fast(sacc[si][2], sacc[si][3]);
            *(u32x2*)(Pw + off) = dw;
        }

        // --- O^T += V^T P^T ---
#pragma unroll
        for (int sc = 0; sc < 2; sc++) {
            bf16x8 pf = *(const bf16x8*)(Pw + (sc * 64 + lane) * 8);
#pragma unroll
            for (int di = 0; di < 4; di++)
                oacc[di] = MFMA16(vf[di][sc], pf, oacc[di]);
        }

        __syncthreads();  // drains next-tile DMA + all LDS reads of buf
        buf ^= 1;
    }

    // epilogue: reduce l across quads, store O^T -> ao[b, t=q, h*64+d]
    const int b = bh >> 4, h = bh & 15;
    float lt = l_;
    lt += __shfl_xor(lt, 16, 64);
    lt += __shfl_xor(lt, 32, 64);
    float inv = 1.0f / lt;
    int q16 = qbase + l16;
#pragma unroll
    for (int di = 0; di < 4; di++) {
        u16x4 pk;
#pragma unroll
        for (int r = 0; r < 4; r++) pk[r] = f2bf(oacc[di][r] * inv);
        *(u16x4*)(ao + (size_t)(b * 2048 + q16) * 1024 +
                  h * 64 + di * 16 + quad * 4) = pk;
    }
}

// ---------------------------------------------------------------------------
// Kernel 3: output projection. out = ao(bf16) @ Wo^T + bo, fp32 out.
// R9: 64x128 tiles -> 512 blocks (2/CU; R6 had 256 = 1/CU), fp32 W staged
// via GLL + frag-time convert (proven pattern), nontemporal fp32 stores
// (output never re-read).
// ---------------------------------------------------------------------------
__global__ __launch_bounds__(256, 2)
void proj_out_kernel(const unsigned short* __restrict__ A,  // [4096][1024] bf16
                     const float* __restrict__ W,           // [1024][1024]
                     const float* __restrict__ bias,
                     float* __restrict__ out)
{
    __shared__ unsigned short As[64 * 32];  // 4 KB, chunk-swizzled
    __shared__ float Bf[128 * 32];          // 16 KB, chunk-swizzled

    const int tid  = threadIdx.x;
    const int lane = tid & 63;
    const int w    = tid >> 6;
    const int l16  = lane & 15;
    const int quad = lane >> 4;
    const int wm   = (w >> 1) * 32;
    const int wn   = (w & 1) * 64;
    const int m0   = blockIdx.y * 64;
    const int n0   = blockIdx.x * 128;

    const int rhiA = lane >> 2;
    const int cgA  = (lane & 3) ^ (rhiA & 3);
    const int rhiB = lane >> 3;
    const int cgB  = (lane & 7) ^ rhiB;

    f32x4 acc[2][4];
#pragma unroll
    for (int i = 0; i < 2; i++)
#pragma unroll
        for (int j = 0; j < 4; j++) {
            f32x4 zv = {0.0f, 0.0f, 0.0f, 0.0f};
            acc[i][j] = zv;
        }

    const int sB  = (2 * quad) ^ (l16 & 7);
    const int sAq = quad ^ (l16 & 3);

    for (int k0 = 0; k0 < 1024; k0 += 32) {
        // A: 64 rows bf16, 1 GLL per wave (16 rows each)
        GLL(A + (size_t)(m0 + w * 16 + rhiA) * 1024 + k0 + cgA * 8, &As[w * 512]);
        // B: 128 rows fp32, 4 GLL per wave (8 rows each)
#pragma unroll
        for (int r = 0; r < 4; r++) {
            int j = w * 4 + r;
            GLL(W + (size_t)(n0 + j * 8 + rhiB) * 1024 + k0 + cgB * 4, &Bf[j * 8 * 32]);
        }
        __syncthreads();

        bf16x8 af[2], bfr[4];
#pragma unroll
        for (int mi = 0; mi < 2; mi++)
            af[mi] = *(const bf16x8*)(&As[(wm + mi * 16 + l16) * 32 + sAq * 8]);
#pragma unroll
        for (int ni = 0; ni < 4; ni++) {
            const float* p = &Bf[(wn + ni * 16 + l16) * 32];
            f32x4 cb0 = *(const f32x4*)(p + sB * 4);
            f32x4 cb1 = *(const f32x4*)(p + (sB ^ 1) * 4);
            bfr[ni] = cvt8(cb0, cb1);
        }
#pragma unroll
        for (int mi = 0; mi < 2; mi++)
#pragma unroll
            for (int ni = 0; ni < 4; ni++)
                acc[mi][ni] = MFMA16(af[mi], bfr[ni], acc[mi][ni]);
        __syncthreads();
    }

#pragma unroll
    for (int ni = 0; ni < 4; ni++) {
        int gn = n0 + wn + ni * 16 + l16;
        float bval = bias[gn];
#pragma unroll
        for (int mi = 0; mi < 2; mi++) {
#pragma unroll
            for (int r = 0; r < 4; r++) {
                int gm = m0 + wm + mi * 16 + quad * 4 + r;
                __builtin_nontemporal_store(acc[mi][ni][r] + bval,
                                            out + (size_t)gm * 1024 + gn);
            }
        }
    }
}

// ---------------------------------------------------------------------------
extern "C" void kernel_launch(void* const* d_in, const int* in_sizes, int n_in,
                              void* d_out, int out_size, void* d_ws, size_t ws_size,
                              hipStream_t stream)
{
    const float* query = (const float*)d_in[0];
    const float* key   = (const float*)d_in[1];
    const float* value = (const float*)d_in[2];
    const float* Wq    = (const float*)d_in[3];
    const float* bq    = (const float*)d_in[4];
    const float* Wk    = (const float*)d_in[5];
    const float* bk    = (const float*)d_in[6];
    const float* Wv    = (const float*)d_in[7];
    const float* bv    = (const float*)d_in[8];
    const float* Wo    = (const float*)d_in[9];
    const float* bo    = (const float*)d_in[10];
    // d_in[11] = query_chunk_size: evaluation-order hint only, ignored.

    unsigned short* qh = (unsigned short*)d_ws;   // [B,H,T,D] bf16 (pre-scaled)
    unsigned short* kh = qh + 4194304;            // [B,H,S,D]
    unsigned short* vt = kh + 4194304;            // [B,H,D,S]  (V transposed)
    unsigned short* ao = vt + 4194304;            // [B,T,C]
    float* out = (float*)d_out;

    proj_qkv_kernel<<<dim3(8, 32, 3), 256, 0, stream>>>(
        query, key, value, Wq, Wk, Wv, bq, bk, bv, qh, kh, vt);
    attn_kernel<<<dim3(32, 32), 256, 0, stream>>>(qh, kh, vt, ao);
    proj_out_kernel<<<dim3(8, 64), 256, 0, stream>>>(ao, Wo, bo, out);
}